// Round 7
// baseline (121.790 us; speedup 1.0000x reference)
//
#include <hip/hip_runtime.h>
#include <math.h>

#define BB 32
#define SS 512
#define HH 256
#define TT 48
#define START_IDX 46
#define STOP_IDX 47

typedef __attribute__((ext_vector_type(8))) short short8;
typedef __attribute__((ext_vector_type(4))) float floatx4;

__device__ __forceinline__ float rfl(float x) {
    return __int_as_float(__builtin_amdgcn_readfirstlane(__float_as_int(x)));
}
__device__ __forceinline__ unsigned int bf16_rne(float x) {
    const unsigned int u = __float_as_uint(x);
    return (u + 0x7fffu + ((u >> 16) & 1u)) >> 16;
}
__device__ __forceinline__ float bf2f(unsigned short h) {
    return __uint_as_float(((unsigned int)h) << 16);
}

// ---------------------------------------------------------------------------
// Kernel 1 (fused): per-(batch,chunk) block computes its 16 emission rows
//   (bf16 MFMA GEMM, K split 3/3/2 across the 3 waves, f32 partial reduce),
//   stores exem bf16 (for finalize gold/terminal), then runs the 16-step
//   product Q_c = PROD(D_t * E) with rows split 16/wave (R6 structure).
// ---------------------------------------------------------------------------
__global__ __launch_bounds__(192) void chunk_fused_kernel(
    const float* __restrict__ f,       // [B*S, H]
    const float* __restrict__ w,       // [H, T]
    const float* __restrict__ bias,    // [T]
    const float* __restrict__ trans,   // [T, T]
    const int*   __restrict__ lengths, // [B]
    unsigned short* __restrict__ exem, // [B*S, T] bf16 out
    unsigned short* __restrict__ Qs,   // [B*32][48][64] bf16 (col-major Q)
    float* __restrict__ Ls3)           // [B*32][3] per-rowblock logscale
{
    __shared__ __align__(16) float elds[16 * TT];        // exp(em) f32, 3 KB
    __shared__ __align__(16) char scratch[9216];         // pbuf / abuf overlay
    float* pbuf = (float*)scratch;                       // [3][16][48] f32
    unsigned short* abuf = (unsigned short*)scratch;     // [3][17*56] bf16

    const int bc = blockIdx.x, b = bc >> 5, c = bc & 31;
    const int len = lengths[b];
    int nsteps = (len - 1) - (c << 4);
    if (nsteps > 16) nsteps = 16;

    const int tid = threadIdx.x;
    const int rb = tid >> 6, l = tid & 63, g = l >> 4, cl = l & 15;

    // ---- E = exp(trans) B-frags, per lane from global (L2-resident) ----
    uint4 BfE[2][3];
#pragma unroll
    for (int kc = 0; kc < 2; ++kc)
#pragma unroll
        for (int nt = 0; nt < 3; ++nt) {
            unsigned int p[4];
#pragma unroll
            for (int h = 0; h < 4; ++h) {
                const int k = kc * 32 + g * 8 + 2 * h;
                const int n = nt * 16 + cl;
                const float lo = (k     < TT) ? __expf(trans[k * TT + n])       : 0.f;
                const float hi = (k + 1 < TT) ? __expf(trans[(k + 1) * TT + n]) : 0.f;
                p[h] = bf16_rne(lo) | (bf16_rne(hi) << 16);
            }
            BfE[kc][nt] = make_uint4(p[0], p[1], p[2], p[3]);
        }

    // ---- emission GEMM, wave rb handles k-tiles [3rb, 3rb+ktn) ----
    const int kt0 = rb * 3;
    const int ktn = (rb < 2) ? 3 : 2;
    const size_t grow = (size_t)(b * SS + c * 16 + cl);  // A row = cl

    floatx4 eacc[3] = {{0.f,0.f,0.f,0.f}, {0.f,0.f,0.f,0.f}, {0.f,0.f,0.f,0.f}};
    for (int kk = 0; kk < ktn; ++kk) {
        const int kt = kt0 + kk;
        const float4 v0 = *(const float4*)(f + grow * HH + kt * 32 + g * 8);
        const float4 v1 = *(const float4*)(f + grow * HH + kt * 32 + g * 8 + 4);
        const unsigned int a0 = bf16_rne(v0.x) | (bf16_rne(v0.y) << 16);
        const unsigned int a1 = bf16_rne(v0.z) | (bf16_rne(v0.w) << 16);
        const unsigned int a2 = bf16_rne(v1.x) | (bf16_rne(v1.y) << 16);
        const unsigned int a3 = bf16_rne(v1.z) | (bf16_rne(v1.w) << 16);
        const short8 Af = __builtin_bit_cast(short8, make_uint4(a0, a1, a2, a3));
#pragma unroll
        for (int nt = 0; nt < 3; ++nt) {
            unsigned int p[4];
#pragma unroll
            for (int h = 0; h < 4; ++h) {
                const int k = kt * 32 + g * 8 + 2 * h;   // < 256 always
                const int n = nt * 16 + cl;
                p[h] = bf16_rne(w[k * TT + n]) | (bf16_rne(w[(k + 1) * TT + n]) << 16);
            }
            eacc[nt] = __builtin_amdgcn_mfma_f32_16x16x32_bf16(
                Af, __builtin_bit_cast(short8, make_uint4(p[0], p[1], p[2], p[3])),
                eacc[nt], 0, 0, 0);
        }
    }
    // partial C -> pbuf  (C layout: row 4g+r, col nt*16+cl)
#pragma unroll
    for (int nt = 0; nt < 3; ++nt)
#pragma unroll
        for (int r = 0; r < 4; ++r)
            pbuf[rb * 768 + (4 * g + r) * TT + nt * 16 + cl] = eacc[nt][r];
    __syncthreads();

    // ---- reduce partials, +bias, exp -> elds f32; store exem bf16 ----
    {
        const int s  = tid / 12;
        const int c0 = (tid - s * 12) * 4;
        const float4 p0 = *(const float4*)&pbuf[       s * TT + c0];
        const float4 p1 = *(const float4*)&pbuf[768  + s * TT + c0];
        const float4 p2 = *(const float4*)&pbuf[1536 + s * TT + c0];
        const float4 bv = *(const float4*)&bias[c0];
        const float e0 = __expf(p0.x + p1.x + p2.x + bv.x);
        const float e1 = __expf(p0.y + p1.y + p2.y + bv.y);
        const float e2 = __expf(p0.z + p1.z + p2.z + bv.z);
        const float e3 = __expf(p0.w + p1.w + p2.w + bv.w);
        *(float4*)&elds[s * TT + c0] = make_float4(e0, e1, e2, e3);
        const unsigned int lo = bf16_rne(e0) | (bf16_rne(e1) << 16);
        const unsigned int hi = bf16_rne(e2) | (bf16_rne(e3) << 16);
        *(uint2*)&exem[((size_t)(b * SS + c * 16 + s)) * TT + c0] = make_uint2(lo, hi);
    }
    __syncthreads();   // elds ready; pbuf dead -> abuf overlay safe

    if (nsteps <= 0) return;   // uniform per block; no barriers below

    // ---- product loop: rows [16rb,16rb+16), private abuf scratch ----
    floatx4 acc[3];
#pragma unroll
    for (int nt = 0; nt < 3; ++nt)
#pragma unroll
        for (int r = 0; r < 4; ++r)
            acc[nt][r] = (16 * rb + 4 * g + r == nt * 16 + cl) ? 1.f : 0.f;

    float ev[3];
#pragma unroll
    for (int nt = 0; nt < 3; ++nt) ev[nt] = elds[nt * 16 + cl];

    float Lrb = 0.f;
    unsigned short* aw = abuf + rb * (17 * 56);

    for (int s = 0; s < nsteps; ++s) {
        float scale = 1.f;
        if (s == 8) {   // one normalization mid-chunk
            const float sig = rfl(acc[0][0]);
            Lrb = __logf(sig);
            scale = __builtin_amdgcn_rcpf(sig);
        }
        const float f0 = ev[0] * scale, f1 = ev[1] * scale, f2 = ev[2] * scale;
#pragma unroll
        for (int r = 0; r < 4; ++r) {
            const int rw = (4 * g + r) * 56;
            aw[rw +      cl] = (unsigned short)bf16_rne(acc[0][r] * f0);
            aw[rw + 16 + cl] = (unsigned short)bf16_rne(acc[1][r] * f1);
            aw[rw + 32 + cl] = (unsigned short)bf16_rne(acc[2][r] * f2);
        }
        if (s + 1 < nsteps) {   // off-chain emission prefetch (f32 LDS)
#pragma unroll
            for (int nt = 0; nt < 3; ++nt)
                ev[nt] = elds[(s + 1) * TT + nt * 16 + cl];
        }
        uint4 a0 = *(const uint4*)&aw[cl * 56 + g * 8];
        uint4 a1 = *(const uint4*)&aw[cl * 56 + 32 + g * 8];
        if (g >= 2) a1 = make_uint4(0, 0, 0, 0);   // k >= 48 pad
        const floatx4 z = {0.f, 0.f, 0.f, 0.f};
#pragma unroll
        for (int nt = 0; nt < 3; ++nt) {
            floatx4 d = __builtin_amdgcn_mfma_f32_16x16x32_bf16(
                __builtin_bit_cast(short8, a0), __builtin_bit_cast(short8, BfE[0][nt]), z, 0, 0, 0);
            d = __builtin_amdgcn_mfma_f32_16x16x32_bf16(
                __builtin_bit_cast(short8, a1), __builtin_bit_cast(short8, BfE[1][nt]), d, 0, 0, 0);
            acc[nt] = d;
        }
    }

    // store col-major Q (qb[col*64 + row])
    unsigned short* qb = Qs + (size_t)bc * (TT * 64);
#pragma unroll
    for (int nt = 0; nt < 3; ++nt) {
        const unsigned int lo = bf16_rne(acc[nt][0]) | (bf16_rne(acc[nt][1]) << 16);
        const unsigned int hi = bf16_rne(acc[nt][2]) | (bf16_rne(acc[nt][3]) << 16);
        *(uint2*)&qb[(nt * 16 + cl) * 64 + 16 * rb + 4 * g] = make_uint2(lo, hi);
    }
    if (l == 0) Ls3[bc * 3 + rb] = Lrb;
}

// ---------------------------------------------------------------------------
// Kernel 2: per-batch combine (serial MFMA matvecs) + gold + output.
//   Rowblock-scale reconciliation factors hoisted out of the loop (fa0==1).
// ---------------------------------------------------------------------------
__global__ __launch_bounds__(64) void finalize_kernel(
    const unsigned short* __restrict__ exem,
    const float* __restrict__ trans,
    const int*   __restrict__ lengths,
    const int*   __restrict__ tags,
    const unsigned short* __restrict__ Qs,
    const float* __restrict__ Ls3,
    float* __restrict__ out)
{
    __shared__ float tlds[TT * TT];
    __shared__ __align__(16) unsigned short vlds[64];
    __shared__ float Lsl[96];
    __shared__ float falds[96];

    const int j = threadIdx.x, b = blockIdx.x, g = j >> 4, cl = j & 15;

    for (int idx = j; idx < TT * TT; idx += 64) tlds[idx] = trans[idx];

    const int len = lengths[b];
    const int nc = (len - 1 + 15) >> 4;
    for (int i = j; i < nc * 3; i += 64) Lsl[i] = Ls3[b * 96 + i];
    __builtin_amdgcn_wave_barrier();
    for (int i = j; i < nc * 3; i += 64)
        falds[i] = __expf(Lsl[i] - Lsl[(i / 3) * 3]);   // fa for each chunk/rowblock
    __builtin_amdgcn_wave_barrier();

    // gold path score
    float gold = 0.f;
    for (int s = j; s < len; s += 64) {
        const int tag  = tags[b * SS + s];
        const int from = (s == 0) ? START_IDX : tags[b * SS + s - 1];
        gold += __logf(bf2f(exem[((size_t)b * SS + s) * TT + tag])) + tlds[from * TT + tag];
    }
    gold += __shfl_xor(gold, 32); gold += __shfl_xor(gold, 16); gold += __shfl_xor(gold, 8);
    gold += __shfl_xor(gold, 4);  gold += __shfl_xor(gold, 2);  gold += __shfl_xor(gold, 1);

    // v init: E[START,:] with chunk-0 rowblock factors folded in
    const float R0 = Lsl[0];
    float vj = 0.f;
    if (j < TT) vj = __expf(tlds[START_IDX * TT + j]) * falds[j >> 4];
    vlds[j] = (unsigned short)bf16_rne(vj);   // j>=48 -> 0 (k-pad)
    float L = R0;

    const unsigned short* qbase = Qs + (size_t)(b * 32) * (TT * 64);
    floatx4 accn[3];
    float inv = 1.f;

    uint4 pB0[3], pB1[3];
#pragma unroll
    for (int nt = 0; nt < 3; ++nt) {
        pB0[nt] = *(const uint4*)&qbase[(nt * 16 + cl) * 64 + g * 8];
        pB1[nt] = *(const uint4*)&qbase[(nt * 16 + cl) * 64 + 32 + g * 8];
    }

    for (int cc = 0; cc < nc; ++cc) {
        uint4 B0[3], B1[3];
#pragma unroll
        for (int nt = 0; nt < 3; ++nt) { B0[nt] = pB0[nt]; B1[nt] = pB1[nt]; }

        const int cn = (cc + 1 < nc) ? cc + 1 : cc;
#pragma unroll
        for (int nt = 0; nt < 3; ++nt) {
            pB0[nt] = *(const uint4*)&qbase[(size_t)cn * TT * 64 + (nt * 16 + cl) * 64 + g * 8];
            pB1[nt] = *(const uint4*)&qbase[(size_t)cn * TT * 64 + (nt * 16 + cl) * 64 + 32 + g * 8];
        }
#pragma unroll
        for (int nt = 0; nt < 3; ++nt)
            if (g >= 2) B1[nt] = make_uint4(0, 0, 0, 0);

        const uint4 A0 = *(const uint4*)&vlds[g * 8];
        const uint4 A1 = *(const uint4*)&vlds[32 + g * 8];

        const floatx4 z = {0.f, 0.f, 0.f, 0.f};
#pragma unroll
        for (int nt = 0; nt < 3; ++nt) {
            floatx4 d = __builtin_amdgcn_mfma_f32_16x16x32_bf16(
                __builtin_bit_cast(short8, A0), __builtin_bit_cast(short8, B0[nt]), z, 0, 0, 0);
            d = __builtin_amdgcn_mfma_f32_16x16x32_bf16(
                __builtin_bit_cast(short8, A1), __builtin_bit_cast(short8, B1[nt]), d, 0, 0, 0);
            accn[nt] = d;
        }

        const float sig = rfl(accn[0][0]);   // > 0 always
        inv = __builtin_amdgcn_rcpf(sig);

        if (cc + 1 < nc) {
            const float Rn  = Lsl[(cc + 1) * 3];
            const float fa1 = falds[(cc + 1) * 3 + 1];
            const float fa2 = falds[(cc + 1) * 3 + 2];
            L += __logf(sig) + Rn;
            if (j < 16) {   // row 0 of result: lanes 0..15, reg 0; fa0 == 1
                vlds[ 0 + j] = (unsigned short)bf16_rne(accn[0][0] * inv);
                vlds[16 + j] = (unsigned short)bf16_rne(accn[1][0] * inv * fa1);
                vlds[32 + j] = (unsigned short)bf16_rne(accn[2][0] * inv * fa2);
            }
        } else {
            L += __logf(sig);
        }
    }

    // terminal: sum_n v[n] * exem[len-1][n] * exp(trans[n][STOP])
    float term = 0.f;
    if (j < 16) {
        const size_t erow = ((size_t)b * SS + (len - 1)) * TT;
#pragma unroll
        for (int nt = 0; nt < 3; ++nt) {
            const int col = nt * 16 + j;
            term += accn[nt][0] * inv * bf2f(exem[erow + col])
                    * __expf(tlds[col * TT + STOP_IDX]);
        }
    }
    term += __shfl_xor(term, 32); term += __shfl_xor(term, 16); term += __shfl_xor(term, 8);
    term += __shfl_xor(term, 4);  term += __shfl_xor(term, 2);  term += __shfl_xor(term, 1);

    if (j == 0) {
        const float all_paths = __logf(term) + L;
        const int last = tags[b * SS + len - 1];
        out[b] = all_paths - (gold + tlds[last * TT + STOP_IDX]);
    }
}

// ---------------------------------------------------------------------------
extern "C" void kernel_launch(void* const* d_in, const int* in_sizes, int n_in,
                              void* d_out, int out_size, void* d_ws, size_t ws_size,
                              hipStream_t stream) {
    const float* f       = (const float*)d_in[0];
    const float* w       = (const float*)d_in[1];
    const float* bias    = (const float*)d_in[2];
    const float* trans   = (const float*)d_in[3];
    const int*   lengths = (const int*)d_in[4];
    const int*   tags    = (const int*)d_in[5];
    float*       out     = (float*)d_out;

    // ws: exem bf16 [B*S*T] | Qs bf16 [B*32*48*64] | Ls3 f32 [B*32*3]
    char* ws = (char*)d_ws;
    unsigned short* exem = (unsigned short*)ws;                  // 1,572,864 B
    unsigned short* Qs   = (unsigned short*)(ws + 1572864);      // 6,291,456 B
    float*          Lsc  = (float*)(ws + 7864320);               // 12,288 B

    chunk_fused_kernel<<<BB * 32, 192, 0, stream>>>(f, w, bias, trans, lengths,
                                                    exem, Qs, Lsc);
    finalize_kernel<<<BB, 64, 0, stream>>>(exem, trans, lengths, tags, Qs, Lsc, out);
}